// Round 5
// baseline (4339.680 us; speedup 1.0000x reference)
//
#include <hip/hip_runtime.h>
#include <cstdint>

#define NS 2048      // states S
#define NE 65536     // arcs E
#define ND 2048      // pdfs D
#define NB 32        // batch
#define NT 500       // frames
#define NGROUPS 32   // 64-state dest groups
#define ELLCAP (2*NE)   // uint2 entries; padded total ~98K < 131072
#define LEAKYF 0.1f
#define NBG 16       // batch groups (2 batches each)
#define NSP 16       // state partitions (128 states each)

// ws byte offsets
#define WS_COUNTS 0
#define WS_CURSOR 8192
#define WS_WIDTHS 16384
#define WS_GBASE  16640
#define WS_TAGS   16896        // 16 bg x 2 par x 32 x 8B = 8192
#define WS_ALBUF  25088        // 2 par x 16 bg x 2048 x 8B = 512 KB
#define WS_ARC    549376       // ELLCAP * 8B = 1 MB

// ---- per-op device-coherent (L3) access, NO cache-wide fences ----
__device__ __forceinline__ void st_pair2(float2* p, float2 v) {
    union { float f[2]; unsigned long long u; } q; q.f[0] = v.x; q.f[1] = v.y;
    __hip_atomic_store(reinterpret_cast<unsigned long long*>(p), q.u,
                       __ATOMIC_RELAXED, __HIP_MEMORY_SCOPE_AGENT);
}
__device__ __forceinline__ float2 ld_pair2(const float2* p) {
    unsigned long long u = __hip_atomic_load(
        reinterpret_cast<const unsigned long long*>(p),
        __ATOMIC_RELAXED, __HIP_MEMORY_SCOPE_AGENT);
    union { unsigned long long u; float f[2]; } q; q.u = u;
    return make_float2(q.f[0], q.f[1]);
}

__global__ void k_init(const float* __restrict__ log_init, float* albuf,
                       uint32_t* counts, uint32_t* cursor, uint2* arcp,
                       unsigned long long* tags, float* out) {
    int tid = blockIdx.x * blockDim.x + threadIdx.x;
    int n = blockDim.x * gridDim.x;
    for (int i = tid; i < NS; i += n) { counts[i] = 0u; cursor[i] = 0u; }
    for (int i = tid; i < ELLCAP; i += n) arcp[i] = make_uint2(0u, 0u);
    for (int i = tid; i < NBG * NS; i += n) {
        int s = i & (NS - 1);
        float a = __expf(log_init[s]);
        reinterpret_cast<float2*>(albuf)[i] = make_float2(a, a);  // parity0: [bg][s]
    }
    // tags[bg][par][32]: par0 slots k<16 -> (tag=0, Tpart_sp=k); k>=16 same for batch1
    for (int i = tid; i < NBG * 64; i += n) {
        int slot = i & 63;
        int par = slot >> 5, k = slot & 31;
        unsigned long long v = 0ull;
        if (par == 0) {
            int spv = k & 15;
            float tp = 0.f;
            for (int j = 0; j < 128; ++j) tp += __expf(log_init[spv * 128 + j]);
            v = ((unsigned long long)__float_as_uint(tp) << 32);  // tag 0
        }
        tags[i] = v;
    }
    if (tid == 0) out[0] = 0.0f;
}

__global__ void k_count(const int* __restrict__ to_state, uint32_t* counts) {
    int e = blockIdx.x * blockDim.x + threadIdx.x;
    if (e < NE) atomicAdd(&counts[to_state[e]], 1u);
}

__global__ void k_widths(const uint32_t* __restrict__ counts, uint32_t* widths, uint32_t* gbase) {
    int g = threadIdx.x;
    if (g < NGROUPS) {
        uint32_t w = 0u;
        for (int i = 0; i < 64; ++i) w = max(w, counts[g*64 + i]);
        widths[g] = w;
    }
    __syncthreads();
    if (threadIdx.x == 0) {
        uint32_t acc = 0u;
        for (int g2 = 0; g2 < NGROUPS; ++g2) { gbase[g2] = acc; acc += widths[g2] * 64u; }
        gbase[NGROUPS] = acc;
    }
}

__global__ void k_scatter(const int* __restrict__ from_state, const int* __restrict__ to_state,
                          const int* __restrict__ pdf_ids, const float* __restrict__ log_w,
                          const uint32_t* __restrict__ gbase, uint32_t* cursor, uint2* arcp) {
    int e = blockIdx.x * blockDim.x + threadIdx.x;
    if (e >= NE) return;
    int s = to_state[e];
    int g = s >> 6;
    uint32_t slot = atomicAdd(&cursor[s], 1u);
    uint32_t pos = gbase[g] + slot * 64u + (uint32_t)(s & 63);
    uint32_t meta = (uint32_t)from_state[e] | ((uint32_t)pdf_ids[e] << 16);
    arcp[pos] = make_uint2(meta, __float_as_uint(__expf(log_w[e])));
}

// 256 persistent WGs: bid = sp*16 + bg  ->  bid%8 = bg%8 (XCD-locked batch groups).
// Tagged-T exchange: writers publish (tag, T_partial) per batch; readers spin 32 tags,
// sum 16 partials in fixed order. Parity-indexed tag arrays make one-ahead safe.
__global__ __launch_bounds__(1024, 1) void k_fwd(
    const float* __restrict__ x, const float* __restrict__ log_init,
    const float* __restrict__ log_final,
    const uint2* __restrict__ arc, const uint32_t* __restrict__ widths,
    const uint32_t* __restrict__ gbase,
    float* __restrict__ albuf, unsigned long long* __restrict__ tags, float* out)
{
    __shared__ __align__(16) float2 e2[NS];        // 16 KB
    __shared__ __align__(16) float2 Xs[2][ND];     // 32 KB double-buffered exp(x)
    __shared__ __align__(16) float2 pt[16][64];    // 8 KB wave partials
    __shared__ __align__(16) float2 Tp[128];       // new-alpha partial sums
    __shared__ __align__(16) float2 red2[16];

    const int tid  = threadIdx.x;
    const int bg   = blockIdx.x & 15;
    const int sp   = blockIdx.x >> 4;
    const int lane = tid & 63;
    const int wid  = tid >> 6;
    const int gs   = wid >> 3;          // which of my 2 dest groups
    const int wsl  = wid & 7;           // slot-slice (8 waves/group)
    const int g    = sp * 2 + gs;

    const float* x0 = x + (size_t)(bg * 2)     * NT * ND;
    const float* x1 = x + (size_t)(bg * 2 + 1) * NT * ND;

    const float cI0 = LEAKYF * __expf(log_init[tid]);
    const float cI1 = LEAKYF * __expf(log_init[tid + 1024]);

    // Xs[0] prologue
    Xs[0][tid]        = make_float2(__expf(x0[tid]),        __expf(x1[tid]));
    Xs[0][tid + 1024] = make_float2(__expf(x0[tid + 1024]), __expf(x1[tid + 1024]));

    const uint32_t gb = gbase[g];
    const int wd = (int)widths[g];
    const uint2* ap = arc + gb + lane;                 // slot i at ap[i*64]
    unsigned long long* mytags = tags + (size_t)bg * 64;   // [par][32]

    float C0 = 0.f, C1 = 0.f;
    __syncthreads();

    for (int t = 0; t < NT; ++t) {
        const int par = t & 1;
        const float2* cbuf = reinterpret_cast<const float2*>(albuf)
                             + ((size_t)par * NBG + bg) * NS;
        float2* nbuf = reinterpret_cast<float2*>(albuf)
                       + ((size_t)(par ^ 1) * NBG + bg) * NS;

        // x(t+1) prefetch into regs
        float pa0, pa1, pb0, pb1;
        const bool pf = (t + 1 < NT);
        if (pf) {
            const size_t o = (size_t)(t + 1) * ND;
            pa0 = x0[o + tid];        pb0 = x1[o + tid];
            pa1 = x0[o + tid + 1024]; pb1 = x1[o + tid + 1024];
        }

        // spin on this parity's 32 tags >= t; extract T partials from payload
        float T0, T1;
        {
            unsigned long long v = 0ull;
            const unsigned long long* tp = mytags + (size_t)par * 32;
            for (;;) {
                if (lane < 32)
                    v = __hip_atomic_load(tp + lane, __ATOMIC_RELAXED,
                                          __HIP_MEMORY_SCOPE_AGENT);
                bool ok = (lane >= 32) || ((uint32_t)v >= (uint32_t)t);
                if (__all(ok)) break;
                __builtin_amdgcn_s_sleep(2);
            }
            __builtin_amdgcn_sched_barrier(0);
            float val = __uint_as_float((uint32_t)(v >> 32));
            T0 = 0.f; T1 = 0.f;
            #pragma unroll
            for (int j = 0; j < 16; ++j)  T0 += __shfl(val, j, 64);
            #pragma unroll
            for (int j = 16; j < 32; ++j) T1 += __shfl(val, j, 64);
        }
        const float i0 = 1.0f / T0, i1 = 1.0f / T1;
        C0 += __logf(T0); C1 += __logf(T1);

        // alpha load (coherent) + leaky/normalize into LDS
        {
            float2 A0 = ld_pair2(cbuf + tid);
            float2 A1 = ld_pair2(cbuf + tid + 1024);
            e2[tid]        = make_float2(A0.x * i0 + cI0, A0.y * i1 + cI0);
            e2[tid + 1024] = make_float2(A1.x * i0 + cI1, A1.y * i1 + cI1);
        }
        __syncthreads();                               // (B) e2 + Xs(t) ready

        // arc pass: one b64 e2-gather + one b64 Xs-gather serve 2 batches
        float2 s1 = make_float2(0.f, 0.f);
        for (int i = wsl; i < wd; i += 8) {
            uint2 A = ap[(size_t)i * 64];
            const float w = __uint_as_float(A.y);
            const int src = (int)(A.x & 0xFFFFu);
            const int pdf = (int)(A.x >> 16);
            float2 ev = e2[src];
            float2 xv = Xs[par][pdf];
            s1.x += ev.x * (w * xv.x);
            s1.y += ev.y * (w * xv.y);
        }
        pt[wid][lane] = s1;
        if (pf) {   // exp into other Xs buffer (no sync needed vs readers of Xs[par])
            Xs[par ^ 1][tid]        = make_float2(__expf(pa0), __expf(pb0));
            Xs[par ^ 1][tid + 1024] = make_float2(__expf(pa1), __expf(pb1));
        }
        __syncthreads();                               // (C) pt ready

        // reduce 8 wave-partials per state; coherent-store my 128 states
        if (tid < 128) {
            const int base = (tid >> 6) * 8;
            const int l = tid & 63;
            float2 r = pt[base][l];
            #pragma unroll
            for (int k = 1; k < 8; ++k) {
                float2 q = pt[base + k][l];
                r.x += q.x; r.y += q.y;
            }
            st_pair2(nbuf + sp * 128 + tid, r);
            Tp[tid] = r;
        }
        __syncthreads();       // (D) all alpha stores drained (vmcnt0/wave), Tp ready

        // publish (tag=t+1, T_partial) into OTHER parity's slots
        if (wid == 0) {
            float2 a = Tp[lane], b = Tp[lane + 64];
            float t0 = a.x + b.x, t1 = a.y + b.y;
            #pragma unroll
            for (int off = 32; off > 0; off >>= 1) {
                t0 += __shfl_down(t0, off, 64);
                t1 += __shfl_down(t1, off, 64);
            }
            if (lane == 0) {
                unsigned long long* np = mytags + (size_t)(par ^ 1) * 32;
                unsigned long long w0 =
                    ((unsigned long long)__float_as_uint(t0) << 32) | (uint32_t)(t + 1);
                unsigned long long w1 =
                    ((unsigned long long)__float_as_uint(t1) << 32) | (uint32_t)(t + 1);
                __hip_atomic_store(np + sp,      w0, __ATOMIC_RELAXED,
                                   __HIP_MEMORY_SCOPE_AGENT);
                __hip_atomic_store(np + 16 + sp, w1, __ATOMIC_RELAXED,
                                   __HIP_MEMORY_SCOPE_AGENT);
            }
        }
        // no trailing sync: next iteration's spin is the gate
    }

    // epilogue: sp==0 WG of each bg reduces final alpha (parity NT&1 == 0)
    if (sp == 0) {
        const int par = NT & 1;
        const unsigned long long* tp = mytags + (size_t)par * 32;
        for (;;) {
            unsigned long long v = 0ull;
            if (lane < 32)
                v = __hip_atomic_load(tp + lane, __ATOMIC_RELAXED,
                                      __HIP_MEMORY_SCOPE_AGENT);
            bool ok = (lane >= 32) || ((uint32_t)v >= (uint32_t)NT);
            if (__all(ok)) break;
            __builtin_amdgcn_s_sleep(2);
        }
        __builtin_amdgcn_sched_barrier(0);
        const float2* fbuf = reinterpret_cast<const float2*>(albuf)
                             + ((size_t)par * NBG + bg) * NS;
        float2 A0 = ld_pair2(fbuf + tid);
        float2 A1 = ld_pair2(fbuf + tid + 1024);
        float f0 = __expf(log_final[tid]);
        float f1 = __expf(log_final[tid + 1024]);
        float s0 = A0.x * f0 + A1.x * f1;
        float s1v = A0.y * f0 + A1.y * f1;
        #pragma unroll
        for (int off = 32; off > 0; off >>= 1) {
            s0  += __shfl_down(s0, off, 64);
            s1v += __shfl_down(s1v, off, 64);
        }
        if (lane == 0) red2[wid] = make_float2(s0, s1v);
        __syncthreads();
        if (tid == 0) {
            float t0 = 0.f, t1 = 0.f;
            #pragma unroll
            for (int j = 0; j < 16; ++j) { t0 += red2[j].x; t1 += red2[j].y; }
            atomicAdd(out, -(__logf(t0) + C0) - (__logf(t1) + C1));
        }
    }
}

extern "C" void kernel_launch(void* const* d_in, const int* in_sizes, int n_in,
                              void* d_out, int out_size, void* d_ws, size_t ws_size,
                              hipStream_t stream) {
    const float* x         = (const float*)d_in[0];
    const float* log_w     = (const float*)d_in[1];
    const float* log_init  = (const float*)d_in[2];
    const float* log_final = (const float*)d_in[3];
    const int*   from_st   = (const int*)d_in[4];
    const int*   to_st     = (const int*)d_in[5];
    const int*   pdf_ids   = (const int*)d_in[6];
    float* out = (float*)d_out;

    uint8_t* ws = (uint8_t*)d_ws;
    uint32_t* counts = (uint32_t*)(ws + WS_COUNTS);
    uint32_t* cursor = (uint32_t*)(ws + WS_CURSOR);
    uint32_t* widths = (uint32_t*)(ws + WS_WIDTHS);
    uint32_t* gbase  = (uint32_t*)(ws + WS_GBASE);
    unsigned long long* tags = (unsigned long long*)(ws + WS_TAGS);
    float*    albuf  = (float*)(ws + WS_ALBUF);
    uint2*    arc    = (uint2*)(ws + WS_ARC);

    k_init   <<<512, 256, 0, stream>>>(log_init, albuf, counts, cursor, arc, tags, out);
    k_count  <<<NE/256, 256, 0, stream>>>(to_st, counts);
    k_widths <<<1, 64, 0, stream>>>(counts, widths, gbase);
    k_scatter<<<NE/256, 256, 0, stream>>>(from_st, to_st, pdf_ids, log_w,
                                          gbase, cursor, arc);
    k_fwd    <<<NSP*NBG, 1024, 0, stream>>>(x, log_init, log_final, arc, widths, gbase,
                                            albuf, tags, out);
}

// Round 6
// 2266.525 us; speedup vs baseline: 1.9147x; 1.9147x over previous
//
#include <hip/hip_runtime.h>
#include <cstdint>

#define NS 2048      // states S
#define NE 65536     // arcs E
#define ND 2048      // pdfs D
#define NB 32        // batch
#define NT 500       // frames
#define NGROUPS 32   // 64-state dest groups
#define ELLCAP (2*NE)   // uint4 entries; padded total ~98K < 131072
#define LEAKYF 0.1f
#define NBG 16       // batch groups (2 batches each)
#define NSP 16       // state partitions (128 states each)

// ws byte offsets
#define WS_COUNTS 0
#define WS_CURSOR 8192
#define WS_WIDTHS 16384
#define WS_GBASE  16640
#define WS_BARCNT 16896      // 16 bg x 128B line
#define WS_ALBUF  20480      // 2 par x 16 bg x 2048 x 8B = 512 KB
#define WS_ARC    544768     // ELLCAP * 16B = 2 MB

// ---- per-op device-coherent (L3) access, NO cache-wide fences ----
__device__ __forceinline__ void st_pair2(float2* p, float2 v) {
    union { float f[2]; unsigned long long u; } q; q.f[0] = v.x; q.f[1] = v.y;
    __hip_atomic_store(reinterpret_cast<unsigned long long*>(p), q.u,
                       __ATOMIC_RELAXED, __HIP_MEMORY_SCOPE_AGENT);
}
__device__ __forceinline__ float2 ld_pair2(const float2* p) {
    unsigned long long u = __hip_atomic_load(
        reinterpret_cast<const unsigned long long*>(p),
        __ATOMIC_RELAXED, __HIP_MEMORY_SCOPE_AGENT);
    union { unsigned long long u; float f[2]; } q; q.u = u;
    return make_float2(q.f[0], q.f[1]);
}

__global__ void k_init(const float* __restrict__ log_init, float* albuf,
                       uint32_t* counts, uint32_t* cursor, uint4* arcp,
                       uint32_t* barcnt, float* out) {
    int tid = blockIdx.x * blockDim.x + threadIdx.x;
    int n = blockDim.x * gridDim.x;
    for (int i = tid; i < NS; i += n) { counts[i] = 0u; cursor[i] = 0u; }
    for (int i = tid; i < ELLCAP; i += n) arcp[i] = make_uint4(0u, 0u, 0u, 0u);
    for (int i = tid; i < NBG * NS; i += n) {
        int s = i & (NS - 1);
        float a = __expf(log_init[s]);
        reinterpret_cast<float2*>(albuf)[i] = make_float2(a, a);  // parity0: [bg][s]
    }
    for (int i = tid; i < NBG * 32; i += n) barcnt[i] = 0u;
    if (tid == 0) out[0] = 0.0f;
}

__global__ void k_count(const int* __restrict__ to_state, uint32_t* counts) {
    int e = blockIdx.x * blockDim.x + threadIdx.x;
    if (e < NE) atomicAdd(&counts[to_state[e]], 1u);
}

__global__ void k_widths(const uint32_t* __restrict__ counts, uint32_t* widths, uint32_t* gbase) {
    int g = threadIdx.x;
    if (g < NGROUPS) {
        uint32_t w = 0u;
        for (int i = 0; i < 64; ++i) w = max(w, counts[g*64 + i]);
        widths[g] = w;
    }
    __syncthreads();
    if (threadIdx.x == 0) {
        uint32_t acc = 0u;
        for (int g2 = 0; g2 < NGROUPS; ++g2) { gbase[g2] = acc; acc += widths[g2] * 64u; }
        gbase[NGROUPS] = acc;
    }
}

__global__ void k_scatter(const int* __restrict__ from_state, const int* __restrict__ to_state,
                          const int* __restrict__ pdf_ids, const float* __restrict__ log_w,
                          const float* __restrict__ log_init,
                          const uint32_t* __restrict__ gbase, uint32_t* cursor, uint4* arcp) {
    int e = blockIdx.x * blockDim.x + threadIdx.x;
    if (e >= NE) return;
    int s = to_state[e];
    int g = s >> 6;
    uint32_t slot = atomicAdd(&cursor[s], 1u);
    uint32_t pos = gbase[g] + slot * 64u + (uint32_t)(s & 63);
    int fs = from_state[e];
    uint32_t meta = (uint32_t)fs | ((uint32_t)pdf_ids[e] << 16);
    float w  = __expf(log_w[e]);
    float w2 = LEAKYF * __expf(log_init[fs]) * w;   // leaky-path weight
    arcp[pos] = make_uint4(meta, __float_as_uint(w), __float_as_uint(w2), 0u);
}

// 256 persistent WGs: bid = sp*16 + bg -> bid%8 = bg%8 (XCD-locked batch groups).
// Raw alpha gathered (normalization folded into output); 3 barriers/step;
// wave-0 tail does reduce+scale+store+release(vmcnt)+arrive+spin.
__global__ __launch_bounds__(1024, 1) void k_fwd(
    const float* __restrict__ x, const float* __restrict__ log_final,
    const uint4* __restrict__ arc, const uint32_t* __restrict__ widths,
    const uint32_t* __restrict__ gbase,
    float* __restrict__ albuf, uint32_t* __restrict__ barcnt, float* out)
{
    __shared__ __align__(16) float2 e2[NS];        // 16 KB raw alpha
    __shared__ __align__(16) float2 Xs[2][ND];     // 32 KB exp(x) double-buffered
    __shared__ __align__(16) float2 pt1[16][64];   // 8 KB main partials
    __shared__ __align__(16) float2 pt2[16][64];   // 8 KB leaky partials
    __shared__ __align__(16) float2 red[16];

    const int tid  = threadIdx.x;
    const int bg   = blockIdx.x & 15;
    const int sp   = blockIdx.x >> 4;
    const int lane = tid & 63;
    const int wid  = tid >> 6;
    const int g    = sp * 2 + (wid >> 3);   // my dest group
    const int wsl  = wid & 7;               // slot-slice (8 waves/group)

    const float* x0 = x + (size_t)(bg * 2)     * NT * ND;
    const float* x1 = x + (size_t)(bg * 2 + 1) * NT * ND;

    // Xs[0] prologue (read after (B2) of t=0)
    Xs[0][tid]        = make_float2(__expf(x0[tid]),        __expf(x1[tid]));
    Xs[0][tid + 1024] = make_float2(__expf(x0[tid + 1024]), __expf(x1[tid + 1024]));

    const int wd = (int)widths[g];
    const uint4* ap = arc + gbase[g] + lane;     // slot i at ap[i*64]
    uint32_t* mycnt = barcnt + bg * 32;          // one line per batch-group

    float C0 = 0.f, C1 = 0.f;

    for (int t = 0; t < NT; ++t) {
        const int par = t & 1;
        const float2* cbuf = reinterpret_cast<const float2*>(albuf)
                             + ((size_t)par * NBG + bg) * NS;
        float2* nbuf = reinterpret_cast<float2*>(albuf)
                       + ((size_t)(par ^ 1) * NBG + bg) * NS;

        // x(t+1) prefetch into regs (independent of the handoff)
        float pa0, pa1, pb0, pb1;
        const bool pf = (t + 1 < NT);
        if (pf) {
            const size_t o = (size_t)(t + 1) * ND;
            pa0 = x0[o + tid];        pb0 = x1[o + tid];
            pa1 = x0[o + tid + 1024]; pb1 = x1[o + tid + 1024];
        }

        __syncthreads();   // (B): wave0 finished spin(t-1) -> albuf[par] readable by all

        // raw alpha -> LDS + wave partial of total mass
        float2 A0 = ld_pair2(cbuf + tid);
        float2 A1 = ld_pair2(cbuf + tid + 1024);
        e2[tid]        = A0;
        e2[tid + 1024] = A1;
        float u0 = A0.x + A1.x, u1 = A0.y + A1.y;
        #pragma unroll
        for (int off = 32; off > 0; off >>= 1) {
            u0 += __shfl_down(u0, off, 64);
            u1 += __shfl_down(u1, off, 64);
        }
        if (lane == 0) red[wid] = make_float2(u0, u1);
        __syncthreads();   // (B2): e2 + red + Xs[par] ready

        // arc pass on RAW alpha: s1 = sum a[src]*w*X ; s2 = sum w2*X
        float2 s1 = make_float2(0.f, 0.f);
        float2 s2 = make_float2(0.f, 0.f);
        for (int i = wsl; i < wd; i += 8) {
            uint4 A = ap[(size_t)i * 64];
            const float w  = __uint_as_float(A.y);
            const float w2 = __uint_as_float(A.z);
            const int src = (int)(A.x & 0xFFFFu);
            const int pdf = (int)(A.x >> 16);
            float2 ev = e2[src];
            float2 xv = Xs[par][pdf];
            s1.x += ev.x * (w * xv.x);
            s1.y += ev.y * (w * xv.y);
            s2.x += w2 * xv.x;
            s2.y += w2 * xv.y;
        }
        pt1[wid][lane] = s1;
        pt2[wid][lane] = s2;
        if (pf) {   // exp into the other Xs buffer (readers of Xs[par] unaffected)
            Xs[par ^ 1][tid]        = make_float2(__expf(pa0), __expf(pb0));
            Xs[par ^ 1][tid + 1024] = make_float2(__expf(pa1), __expf(pb1));
        }
        __syncthreads();   // (C): pt ready

        // wave-0 tail: reduce, scale by invT, store 128 states, release, arrive, spin
        if (wid == 0) {
            float2 r1a = pt1[0][lane], r2a = pt2[0][lane];
            float2 r1b = pt1[8][lane], r2b = pt2[8][lane];
            #pragma unroll
            for (int k = 1; k < 8; ++k) {
                float2 q;
                q = pt1[k][lane];     r1a.x += q.x; r1a.y += q.y;
                q = pt2[k][lane];     r2a.x += q.x; r2a.y += q.y;
                q = pt1[8 + k][lane]; r1b.x += q.x; r1b.y += q.y;
                q = pt2[8 + k][lane]; r2b.x += q.x; r2b.y += q.y;
            }
            float T0 = 0.f, T1 = 0.f;
            #pragma unroll
            for (int j = 0; j < 16; ++j) { float2 q = red[j]; T0 += q.x; T1 += q.y; }
            const float i0 = 1.0f / T0, i1 = 1.0f / T1;
            C0 += __logf(T0); C1 += __logf(T1);
            st_pair2(nbuf + sp * 128 + lane,
                     make_float2(r1a.x * i0 + r2a.x, r1a.y * i1 + r2a.y));
            st_pair2(nbuf + sp * 128 + 64 + lane,
                     make_float2(r1b.x * i0 + r2b.x, r1b.y * i1 + r2b.y));
            // wave-scope release: drain coherent stores (already at L3) -- no cache flush
            asm volatile("s_waitcnt vmcnt(0)" ::: "memory");
            if (lane == 0) {
                __hip_atomic_fetch_add(mycnt, 1u, __ATOMIC_RELAXED,
                                       __HIP_MEMORY_SCOPE_AGENT);
                const uint32_t tgt = 16u * (uint32_t)(t + 1);
                while (__hip_atomic_load(mycnt, __ATOMIC_RELAXED,
                                         __HIP_MEMORY_SCOPE_AGENT) < tgt)
                    __builtin_amdgcn_s_sleep(1);
            }
        }
        // other waves run ahead to (B) of t+1 and wait there for wave 0
    }
    __syncthreads();   // all waves gated behind final spin

    // epilogue: sp==0 WG per batch-group; final raw alpha in parity 0 (NT even)
    if (sp == 0) {
        const float2* fbuf = reinterpret_cast<const float2*>(albuf) + (size_t)bg * NS;
        float2 A0 = ld_pair2(fbuf + tid);
        float2 A1 = ld_pair2(fbuf + tid + 1024);
        float f0 = __expf(log_final[tid]);
        float f1 = __expf(log_final[tid + 1024]);
        float u0 = A0.x * f0 + A1.x * f1;
        float u1 = A0.y * f0 + A1.y * f1;
        #pragma unroll
        for (int off = 32; off > 0; off >>= 1) {
            u0 += __shfl_down(u0, off, 64);
            u1 += __shfl_down(u1, off, 64);
        }
        if (lane == 0) red[wid] = make_float2(u0, u1);
        __syncthreads();
        if (tid == 0) {
            float t0 = 0.f, t1 = 0.f;
            #pragma unroll
            for (int j = 0; j < 16; ++j) { t0 += red[j].x; t1 += red[j].y; }
            atomicAdd(out, -(__logf(t0) + C0) - (__logf(t1) + C1));
        }
    }
}

extern "C" void kernel_launch(void* const* d_in, const int* in_sizes, int n_in,
                              void* d_out, int out_size, void* d_ws, size_t ws_size,
                              hipStream_t stream) {
    const float* x         = (const float*)d_in[0];
    const float* log_w     = (const float*)d_in[1];
    const float* log_init  = (const float*)d_in[2];
    const float* log_final = (const float*)d_in[3];
    const int*   from_st   = (const int*)d_in[4];
    const int*   to_st     = (const int*)d_in[5];
    const int*   pdf_ids   = (const int*)d_in[6];
    float* out = (float*)d_out;

    uint8_t* ws = (uint8_t*)d_ws;
    uint32_t* counts = (uint32_t*)(ws + WS_COUNTS);
    uint32_t* cursor = (uint32_t*)(ws + WS_CURSOR);
    uint32_t* widths = (uint32_t*)(ws + WS_WIDTHS);
    uint32_t* gbase  = (uint32_t*)(ws + WS_GBASE);
    uint32_t* barcnt = (uint32_t*)(ws + WS_BARCNT);
    float*    albuf  = (float*)(ws + WS_ALBUF);
    uint4*    arc    = (uint4*)(ws + WS_ARC);

    k_init   <<<512, 256, 0, stream>>>(log_init, albuf, counts, cursor, arc, barcnt, out);
    k_count  <<<NE/256, 256, 0, stream>>>(to_st, counts);
    k_widths <<<1, 64, 0, stream>>>(counts, widths, gbase);
    k_scatter<<<NE/256, 256, 0, stream>>>(from_st, to_st, pdf_ids, log_w, log_init,
                                          gbase, cursor, arc);
    k_fwd    <<<NSP*NBG, 1024, 0, stream>>>(x, log_final, arc, widths, gbase,
                                            albuf, barcnt, out);
}